// Round 1
// baseline (1950.601 us; speedup 1.0000x reference)
//
#include <hip/hip_runtime.h>

// ---------------- problem constants ----------------
#define T_STEPS 512
#define BATCH_N 256
#define IDIM    128
#define NDIM    1024
#define ODIM    10

// decomposition: 16 batch-groups (16 rows each) x 16 n-slices (64 cols each) = 256 WGs
#define AGRP 16
#define BSLC 16
#define BB   16
#define NS   64
#define THREADS 256

// ---------------- workspace layout (bytes) ----------------
#define BATCH_BYTES (33554432ull)                 // bf16 batch [512][256][128]
#define YBUF_OFF    (33554432ull)
#define YBUF_HALF   (524288ull)                   // bf16 [16][16][1024] per buffer
#define SEQ_OFF     (YBUF_OFF + 2*YBUF_HALF)     // 34,603,008
#define SEQ_BYTES   (4096ull)
#define XT_OFF      (SEQ_OFF + SEQ_BYTES)        // 34,607,104
#define XT_BYTES    (1048576ull)                  // fp32 [256][1024]
#define WS_NEED     (XT_OFF + XT_BYTES)

typedef short    s16x8 __attribute__((ext_vector_type(8)));
typedef float    f32x4 __attribute__((ext_vector_type(4)));
typedef unsigned u32x4 __attribute__((ext_vector_type(4)));

__device__ __forceinline__ unsigned short f2bf(float f) {
  unsigned u = __builtin_bit_cast(unsigned, f);
  u += 0x7fffu + ((u >> 16) & 1u);               // RTNE
  return (unsigned short)(u >> 16);
}

// ---------------- batch fp32 -> bf16 prepass ----------------
__global__ void horn_convert(const float* __restrict__ src, unsigned short* __restrict__ dst) {
  size_t gid = (size_t)blockIdx.x * 256 + threadIdx.x;     // 8192*256 threads, 8 elems each
  const f32x4* s4 = reinterpret_cast<const f32x4*>(src) + gid * 2;
  f32x4 a = s4[0], b = s4[1];
  u32x4 o;
  o[0] = (unsigned)f2bf(a[0]) | ((unsigned)f2bf(a[1]) << 16);
  o[1] = (unsigned)f2bf(a[2]) | ((unsigned)f2bf(a[3]) << 16);
  o[2] = (unsigned)f2bf(b[0]) | ((unsigned)f2bf(b[1]) << 16);
  o[3] = (unsigned)f2bf(b[2]) | ((unsigned)f2bf(b[3]) << 16);
  reinterpret_cast<u32x4*>(dst)[gid] = o;
}

// ---------------- persistent recurrent kernel ----------------
// LDS: [0,131072)  W-slice bf16 [64 rows][1024 k], scaled by 1/32, XOR-swizzled
//      [131072,163840) y-stage bf16 [16 rows][1024 k], XOR-swizzled
__launch_bounds__(THREADS, 1)
__global__ void horn_persistent(const unsigned short* __restrict__ batchbf,
                                const float* __restrict__ i2h_w,
                                const float* __restrict__ i2h_b,
                                const float* __restrict__ h2h_w,
                                const float* __restrict__ h2h_b,
                                unsigned short* ybuf,     // [2][16][16][1024] bf16
                                unsigned int*  seq,       // [16][16]
                                float* xT)                // [256][1024] fp32
{
  extern __shared__ char smem[];
  const int tid  = threadIdx.x;
  const int lane = tid & 63;
  const int wv   = tid >> 6;          // wave 0..3
  const int blk  = blockIdx.x;
  const int ig   = blk & 15;          // batch group
  const int jg   = blk >> 4;          // n-slice
  const int l15  = lane & 15;
  const int kb   = lane >> 4;         // k-block 0..3 within fragment

  // ---- stage W slice -> LDS (once): rows jg*64 .. +64, scaled by GAIN=1/32 ----
  for (int idx = tid; idx < NS * 128; idx += THREADS) {
    int row = idx >> 7;               // 0..63
    int c16 = idx & 127;              // 16-byte chunk (8 bf16) within row
    const f32x4* g = reinterpret_cast<const f32x4*>(h2h_w + (size_t)(jg * NS + row) * NDIM + c16 * 8);
    f32x4 a = g[0], b = g[1];
    u32x4 o;
    o[0] = (unsigned)f2bf(a[0]*0.03125f) | ((unsigned)f2bf(a[1]*0.03125f) << 16);
    o[1] = (unsigned)f2bf(a[2]*0.03125f) | ((unsigned)f2bf(a[3]*0.03125f) << 16);
    o[2] = (unsigned)f2bf(b[0]*0.03125f) | ((unsigned)f2bf(b[1]*0.03125f) << 16);
    o[3] = (unsigned)f2bf(b[2]*0.03125f) | ((unsigned)f2bf(b[3]*0.03125f) << 16);
    int off = row * 2048 + ((c16 * 16) ^ ((row & 7) << 4));
    *reinterpret_cast<u32x4*>(smem + off) = o;
  }

  // ---- i2h B-fragments (permanently in VGPRs) + fused bias ----
  const int jc = jg * NS + wv * 16 + l15;        // my output column
  s16x8 i2hf[4];
  #pragma unroll
  for (int kc = 0; kc < 4; ++kc) {
    const float* g = i2h_w + (size_t)jc * IDIM + kc * 32 + kb * 8;
    s16x8 v;
    #pragma unroll
    for (int e = 0; e < 8; ++e) v[e] = (short)f2bf(g[e]);
    i2hf[kc] = v;
  }
  const float bias = i2h_b[jc] + h2h_b[jc] * 0.03125f;   // i2h_b + GAIN*h2h_b

  __syncthreads();

  float xs[4] = {0.f,0.f,0.f,0.f};
  float ys[4] = {0.f,0.f,0.f,0.f};
  unsigned int* sp = seq + ig * 16;

  for (int t = 0; t < T_STEPS; ++t) {
    // ---- u-phase: acc = bias + batch_t @ i2h^T (independent of state) ----
    f32x4 acc = {bias, bias, bias, bias};
    {
      const unsigned short* bp = batchbf + ((size_t)t * BATCH_N + ig * BB + l15) * IDIM + kb * 8;
      #pragma unroll
      for (int kc = 0; kc < 4; ++kc) {
        s16x8 a = *reinterpret_cast<const s16x8*>(bp + kc * 32);
        acc = __builtin_amdgcn_mfma_f32_16x16x32_bf16(a, i2hf[kc], acc, 0, 0, 0);
      }
    }
    // ---- wait for all 16 peers of this batch-group to have published y_t ----
    if (wv == 0) {
      while (true) {
        unsigned v = 0xFFFFFFFFu;
        if (lane < 16) v = atomicAdd(sp + lane, 0u);     // coherent RMW read
        if (__all((int)(v >= (unsigned)t))) break;
        __builtin_amdgcn_s_sleep(2);
      }
    }
    __syncthreads();

    // ---- stage y_t [16][1024] bf16 global(LLC) -> LDS (swizzled) ----
    {
      const char* gy = (const char*)ybuf + (size_t)(t & 1) * YBUF_HALF + (size_t)ig * (BB * NDIM * 2);
      const u32x4* g4 = reinterpret_cast<const u32x4*>(gy) + tid;
      u32x4 v0, v1, v2, v3, v4, v5, v6, v7;
      asm volatile(
        "global_load_dwordx4 %0, %8, off sc0 sc1\n\t"
        "global_load_dwordx4 %1, %9, off sc0 sc1\n\t"
        "global_load_dwordx4 %2, %10, off sc0 sc1\n\t"
        "global_load_dwordx4 %3, %11, off sc0 sc1\n\t"
        "global_load_dwordx4 %4, %12, off sc0 sc1\n\t"
        "global_load_dwordx4 %5, %13, off sc0 sc1\n\t"
        "global_load_dwordx4 %6, %14, off sc0 sc1\n\t"
        "global_load_dwordx4 %7, %15, off sc0 sc1\n\t"
        "s_waitcnt vmcnt(0)"
        : "=&v"(v0), "=&v"(v1), "=&v"(v2), "=&v"(v3),
          "=&v"(v4), "=&v"(v5), "=&v"(v6), "=&v"(v7)
        : "v"(g4), "v"(g4+256), "v"(g4+512), "v"(g4+768),
          "v"(g4+1024), "v"(g4+1280), "v"(g4+1536), "v"(g4+1792)
        : "memory");
      #define STG(r, vr) { int idx = tid + (r)*256; \
        *reinterpret_cast<u32x4*>(smem + 131072 + ((idx*16) ^ (((idx>>7)&7)<<4))) = vr; }
      STG(0, v0) STG(1, v1) STG(2, v2) STG(3, v3)
      STG(4, v4) STG(5, v5) STG(6, v6) STG(7, v7)
      #undef STG
    }
    __syncthreads();

    // ---- rec-phase: acc += y_t @ (W/32)^T for my 16-col tile ----
    {
      const char* ybase = smem + 131072 + l15 * 2048;
      const char* wbase = smem + (wv * 16 + l15) * 2048;
      const int swz = (l15 & 7) << 4;
      #pragma unroll 8
      for (int kc = 0; kc < 32; ++kc) {
        int ko = kc * 64 + kb * 16;
        s16x8 a = *reinterpret_cast<const s16x8*>(ybase + (ko ^ swz));
        s16x8 b = *reinterpret_cast<const s16x8*>(wbase + (ko ^ swz));
        acc = __builtin_amdgcn_mfma_f32_16x16x32_bf16(a, b, acc, 0, 0, 0);
      }
    }

    // ---- state update (fp32, in registers) ----
    unsigned yw0, yw1, yw2, yw3;
    {
      float z, th, yn;
      z = acc[0]; th = tanhf(z); yn = ys[0] + 0.1f*(th - xs[0] - 0.2f*ys[0]); xs[0] += 0.1f*yn; ys[0] = yn; yw0 = f2bf(yn);
      z = acc[1]; th = tanhf(z); yn = ys[1] + 0.1f*(th - xs[1] - 0.2f*ys[1]); xs[1] += 0.1f*yn; ys[1] = yn; yw1 = f2bf(yn);
      z = acc[2]; th = tanhf(z); yn = ys[2] + 0.1f*(th - xs[2] - 0.2f*ys[2]); xs[2] += 0.1f*yn; ys[2] = yn; yw2 = f2bf(yn);
      z = acc[3]; th = tanhf(z); yn = ys[3] + 0.1f*(th - xs[3] - 0.2f*ys[3]); xs[3] += 0.1f*yn; ys[3] = yn; yw3 = f2bf(yn);
    }

    // ---- publish y_{t+1} block to the other buffer (device-coherent stores) ----
    {
      unsigned short* wp = ybuf + (size_t)((t + 1) & 1) * 262144 + (size_t)ig * (BB * NDIM) + jc;
      asm volatile(
        "global_store_short %4, %0, off sc0 sc1\n\t"
        "global_store_short %5, %1, off sc0 sc1\n\t"
        "global_store_short %6, %2, off sc0 sc1\n\t"
        "global_store_short %7, %3, off sc0 sc1\n\t"
        "s_waitcnt vmcnt(0)"
        :
        : "v"(yw0), "v"(yw1), "v"(yw2), "v"(yw3),
          "v"(wp + (size_t)(kb*4+0)*NDIM), "v"(wp + (size_t)(kb*4+1)*NDIM),
          "v"(wp + (size_t)(kb*4+2)*NDIM), "v"(wp + (size_t)(kb*4+3)*NDIM)
        : "memory");
    }
    __syncthreads();                       // all waves' stores drained (vmcnt inside asm)
    if (tid == 0) atomicAdd(sp + jg, 1u);  // seq[ig][jg] = t+1 (device-scope RMW)
  }

  // ---- write x_T ----
  #pragma unroll
  for (int q = 0; q < 4; ++q) {
    int row = ig * BB + kb * 4 + q;
    xT[(size_t)row * NDIM + jc] = xs[q];
  }
}

// ---------------- final readout: out = x_T @ h2o^T + b ----------------
__global__ void horn_out(const float* __restrict__ xT, const float* __restrict__ h2o_w,
                         const float* __restrict__ h2o_b, float* __restrict__ out) {
  int b = blockIdx.x;
  int lane = threadIdx.x;                  // 64 threads
  float p[ODIM];
  #pragma unroll
  for (int o = 0; o < ODIM; ++o) p[o] = 0.f;
  for (int it = 0; it < NDIM / 64; ++it) {
    int n = it * 64 + lane;
    float xv = xT[(size_t)b * NDIM + n];
    #pragma unroll
    for (int o = 0; o < ODIM; ++o) p[o] += xv * h2o_w[o * NDIM + n];
  }
  #pragma unroll
  for (int o = 0; o < ODIM; ++o) {
    float v = p[o];
    #pragma unroll
    for (int off = 32; off >= 1; off >>= 1) v += __shfl_down(v, off, 64);
    if (lane == 0) out[b * ODIM + o] = v + h2o_b[o];
  }
}

__global__ void horn_fail(float* out) {    // loud sentinel if ws too small
  int i = blockIdx.x * 256 + threadIdx.x;
  if (i < BATCH_N * ODIM) out[i] = 12345.0f;
}

extern "C" void kernel_launch(void* const* d_in, const int* in_sizes, int n_in,
                              void* d_out, int out_size, void* d_ws, size_t ws_size,
                              hipStream_t stream) {
  const float* batch = (const float*)d_in[0];
  const float* i2h_w = (const float*)d_in[1];
  const float* i2h_b = (const float*)d_in[2];
  const float* h2h_w = (const float*)d_in[3];
  const float* h2h_b = (const float*)d_in[4];
  const float* h2o_w = (const float*)d_in[5];
  const float* h2o_b = (const float*)d_in[6];
  float* out = (float*)d_out;
  char* ws = (char*)d_ws;

  if (ws_size < WS_NEED) {
    horn_fail<<<16, 256, 0, stream>>>(out);
    return;
  }

  (void)hipFuncSetAttribute(reinterpret_cast<const void*>(horn_persistent),
                            hipFuncAttributeMaxDynamicSharedMemorySize, 163840);

  hipMemsetAsync(ws + YBUF_OFF, 0, YBUF_HALF, stream);   // y_0 = 0
  hipMemsetAsync(ws + SEQ_OFF, 0, SEQ_BYTES, stream);    // seq = 0

  horn_convert<<<8192, 256, 0, stream>>>(batch, (unsigned short*)(ws + 0));

  horn_persistent<<<AGRP * BSLC, THREADS, 163840, stream>>>(
      (const unsigned short*)(ws + 0), i2h_w, i2h_b, h2h_w, h2h_b,
      (unsigned short*)(ws + YBUF_OFF), (unsigned int*)(ws + SEQ_OFF),
      (float*)(ws + XT_OFF));

  horn_out<<<BATCH_N, 64, 0, stream>>>((const float*)(ws + XT_OFF), h2o_w, h2o_b, out);
}

// Round 2
// 1582.838 us; speedup vs baseline: 1.2323x; 1.2323x over previous
//
#include <hip/hip_runtime.h>

// ---------------- problem constants ----------------
#define T_STEPS 512
#define BATCH_N 256
#define IDIM    128
#define NDIM    1024
#define ODIM    10

// decomposition: 16 batch-groups (16 rows) x 16 n-slices (64 cols) = 256 WGs
#define AGRP 16
#define BSLC 16
#define BB   16
#define NS   64
#define THREADS 256
#define GAIN 0.03125f

// ---------------- workspace layout (bytes) ----------------
#define BATCH_BYTES (33554432ull)                 // bf16 batch [512][256][128]
#define YBUF_OFF    (33554432ull)
#define YBUF_HALF   (524288ull)                   // bf16 [16][16][1024] per buffer
#define SEQ_OFF     (YBUF_OFF + 2*YBUF_HALF)
#define SEQ_BYTES   (4096ull)                     // 16 counters, 128B apart
#define XT_OFF      (SEQ_OFF + SEQ_BYTES)
#define XT_BYTES    (1048576ull)                  // fp32 [256][1024]
#define WS_NEED     (XT_OFF + XT_BYTES)

typedef short    s16x8 __attribute__((ext_vector_type(8)));
typedef float    f32x4 __attribute__((ext_vector_type(4)));
typedef unsigned u32x4 __attribute__((ext_vector_type(4)));

__device__ __forceinline__ unsigned short f2bf(float f) {
  unsigned u = __builtin_bit_cast(unsigned, f);
  u += 0x7fffu + ((u >> 16) & 1u);               // RTNE
  return (unsigned short)(u >> 16);
}

// ---------------- batch fp32 -> bf16 prepass ----------------
__global__ void horn_convert(const float* __restrict__ src, unsigned short* __restrict__ dst) {
  size_t gid = (size_t)blockIdx.x * 256 + threadIdx.x;
  const f32x4* s4 = reinterpret_cast<const f32x4*>(src) + gid * 2;
  f32x4 a = s4[0], b = s4[1];
  u32x4 o;
  o[0] = (unsigned)f2bf(a[0]) | ((unsigned)f2bf(a[1]) << 16);
  o[1] = (unsigned)f2bf(a[2]) | ((unsigned)f2bf(a[3]) << 16);
  o[2] = (unsigned)f2bf(b[0]) | ((unsigned)f2bf(b[1]) << 16);
  o[3] = (unsigned)f2bf(b[2]) | ((unsigned)f2bf(b[3]) << 16);
  reinterpret_cast<u32x4*>(dst)[gid] = o;
}

// ---------------- persistent recurrent kernel ----------------
// LDS: [0,32768) y-stage bf16 [16 rows][1024 k], XOR-swizzled.
// W slice (64 cols x 1024 k, pre-scaled by GAIN) lives in VGPRs (32x s16x8/lane).
__launch_bounds__(THREADS, 1)
__global__ void horn_persistent(const unsigned short* __restrict__ batchbf,
                                const float* __restrict__ i2h_w,
                                const float* __restrict__ i2h_b,
                                const float* __restrict__ h2h_w,
                                const float* __restrict__ h2h_b,
                                unsigned short* ybuf,     // [2][16][16][1024] bf16
                                unsigned int*  seq,       // [16] counters, 32-uint stride
                                float* xT)                // [256][1024] fp32
{
  __shared__ char smem[32768];
  const int tid  = threadIdx.x;
  const int lane = tid & 63;
  const int wv   = tid >> 6;          // wave 0..3
  const int blk  = blockIdx.x;
  const int ig   = blk & 15;          // batch group
  const int jg   = blk >> 4;          // n-slice
  const int l15  = lane & 15;
  const int kb   = lane >> 4;         // k-sub within fragment
  const int jc   = jg * NS + wv * 16 + l15;      // my output column

  // ---- W fragments (permanently in VGPRs): B-frag for col jc, all K ----
  s16x8 wfrag[32];
  #pragma unroll
  for (int kc = 0; kc < 32; ++kc) {
    const f32x4* g = reinterpret_cast<const f32x4*>(h2h_w + (size_t)jc * NDIM + kc * 32 + kb * 8);
    f32x4 a = g[0], b = g[1];
    s16x8 v;
    v[0] = (short)f2bf(a[0]*GAIN); v[1] = (short)f2bf(a[1]*GAIN);
    v[2] = (short)f2bf(a[2]*GAIN); v[3] = (short)f2bf(a[3]*GAIN);
    v[4] = (short)f2bf(b[0]*GAIN); v[5] = (short)f2bf(b[1]*GAIN);
    v[6] = (short)f2bf(b[2]*GAIN); v[7] = (short)f2bf(b[3]*GAIN);
    wfrag[kc] = v;
  }

  // ---- i2h B-fragments (VGPRs) + fused bias ----
  s16x8 i2hf[4];
  #pragma unroll
  for (int kc = 0; kc < 4; ++kc) {
    const float* g = i2h_w + (size_t)jc * IDIM + kc * 32 + kb * 8;
    s16x8 v;
    #pragma unroll
    for (int e = 0; e < 8; ++e) v[e] = (short)f2bf(g[e]);
    i2hf[kc] = v;
  }
  const float bias = i2h_b[jc] + h2h_b[jc] * GAIN;

  // ---- batch fragments for t=0 (prefetched each step thereafter) ----
  s16x8 bfr[4];
  {
    const unsigned short* bp = batchbf + ((size_t)ig * BB + l15) * IDIM + kb * 8;
    #pragma unroll
    for (int kc = 0; kc < 4; ++kc) bfr[kc] = *reinterpret_cast<const s16x8*>(bp + kc * 32);
  }

  float xs[4] = {0.f,0.f,0.f,0.f};
  float ys[4] = {0.f,0.f,0.f,0.f};
  unsigned int* cnt = seq + ig * 32;             // 128B-padded counter per group

  for (int t = 0; t < T_STEPS; ++t) {
    // ---- poll: all 64 waves of this group have published y_t ----
    if (t > 0) {
      const unsigned target = 64u * (unsigned)t;
      while (true) {
        unsigned v = 0;
        if (lane == 0) v = atomicAdd(cnt, 0u);   // coherent RMW read at LLC
        v = (unsigned)__shfl((int)v, 0, 64);
        if (v >= target) break;
        __builtin_amdgcn_s_sleep(1);
      }
    }

    // ---- issue y_t loads (LLC-coherent), no wait yet ----
    const char* gy = (const char*)ybuf + (size_t)(t & 1) * YBUF_HALF + (size_t)ig * (BB * NDIM * 2);
    const u32x4* g4 = reinterpret_cast<const u32x4*>(gy) + tid;
    u32x4 v0, v1, v2, v3, v4, v5, v6, v7;
    asm volatile(
      "global_load_dwordx4 %0, %8, off sc0 sc1\n\t"
      "global_load_dwordx4 %1, %9, off sc0 sc1\n\t"
      "global_load_dwordx4 %2, %10, off sc0 sc1\n\t"
      "global_load_dwordx4 %3, %11, off sc0 sc1\n\t"
      "global_load_dwordx4 %4, %12, off sc0 sc1\n\t"
      "global_load_dwordx4 %5, %13, off sc0 sc1\n\t"
      "global_load_dwordx4 %6, %14, off sc0 sc1\n\t"
      "global_load_dwordx4 %7, %15, off sc0 sc1"
      : "=&v"(v0), "=&v"(v1), "=&v"(v2), "=&v"(v3),
        "=&v"(v4), "=&v"(v5), "=&v"(v6), "=&v"(v7)
      : "v"(g4), "v"(g4+256), "v"(g4+512), "v"(g4+768),
        "v"(g4+1024), "v"(g4+1280), "v"(g4+1536), "v"(g4+1792)
      : "memory");

    // ---- u-phase under the LLC load shadow: acc = bias + batch_t @ i2h^T ----
    f32x4 acc = {bias, bias, bias, bias};
    #pragma unroll
    for (int kc = 0; kc < 4; ++kc)
      acc = __builtin_amdgcn_mfma_f32_16x16x32_bf16(bfr[kc], i2hf[kc], acc, 0, 0, 0);

    // ---- drain y loads, stage to LDS (swizzled) ----
    asm volatile("s_waitcnt vmcnt(0)" ::: "memory");
    #define STG(r, vr) { int idx = tid + (r)*256; \
      *reinterpret_cast<u32x4*>(smem + ((idx*16) ^ (((idx>>7)&7)<<4))) = vr; }
    STG(0, v0) STG(1, v1) STG(2, v2) STG(3, v3)
    STG(4, v4) STG(5, v5) STG(6, v6) STG(7, v7)
    #undef STG
    __syncthreads();                             // the ONE barrier per step

    // ---- prefetch batch for t+1 (completes during rec / next poll) ----
    {
      const int tn = (t + 1 < T_STEPS) ? (t + 1) : t;
      const unsigned short* bp = batchbf + ((size_t)tn * BATCH_N + ig * BB + l15) * IDIM + kb * 8;
      #pragma unroll
      for (int kc = 0; kc < 4; ++kc) bfr[kc] = *reinterpret_cast<const s16x8*>(bp + kc * 32);
    }

    // ---- rec-phase: acc += y_t @ (W*GAIN)^T, W from VGPRs ----
    {
      const char* ybase = smem + l15 * 2048;
      const int swz = (l15 & 7) << 4;
      #pragma unroll
      for (int kc = 0; kc < 32; ++kc) {
        int ko = kc * 64 + kb * 16;
        s16x8 a = *reinterpret_cast<const s16x8*>(ybase + (ko ^ swz));
        acc = __builtin_amdgcn_mfma_f32_16x16x32_bf16(a, wfrag[kc], acc, 0, 0, 0);
      }
    }

    // ---- state update (fp32, registers) ----
    unsigned yw0, yw1, yw2, yw3;
    {
      float z, th, yn;
      z = acc[0]; th = tanhf(z); yn = ys[0] + 0.1f*(th - xs[0] - 0.2f*ys[0]); xs[0] += 0.1f*yn; ys[0] = yn; yw0 = f2bf(yn);
      z = acc[1]; th = tanhf(z); yn = ys[1] + 0.1f*(th - xs[1] - 0.2f*ys[1]); xs[1] += 0.1f*yn; ys[1] = yn; yw1 = f2bf(yn);
      z = acc[2]; th = tanhf(z); yn = ys[2] + 0.1f*(th - xs[2] - 0.2f*ys[2]); xs[2] += 0.1f*yn; ys[2] = yn; yw2 = f2bf(yn);
      z = acc[3]; th = tanhf(z); yn = ys[3] + 0.1f*(th - xs[3] - 0.2f*ys[3]); xs[3] += 0.1f*yn; ys[3] = yn; yw3 = f2bf(yn);
    }

    // ---- publish y_{t+1} (coherent stores, drained), then count this wave ----
    {
      unsigned short* wp = ybuf + (size_t)((t + 1) & 1) * 262144 + (size_t)ig * (BB * NDIM) + jc;
      asm volatile(
        "global_store_short %4, %0, off sc0 sc1\n\t"
        "global_store_short %5, %1, off sc0 sc1\n\t"
        "global_store_short %6, %2, off sc0 sc1\n\t"
        "global_store_short %7, %3, off sc0 sc1\n\t"
        "s_waitcnt vmcnt(0)"
        :
        : "v"(yw0), "v"(yw1), "v"(yw2), "v"(yw3),
          "v"(wp + (size_t)(kb*4+0)*NDIM), "v"(wp + (size_t)(kb*4+1)*NDIM),
          "v"(wp + (size_t)(kb*4+2)*NDIM), "v"(wp + (size_t)(kb*4+3)*NDIM)
        : "memory");
    }
    if (lane == 0) atomicAdd(cnt, 1u);           // per-wave increment (device-scope RMW)
  }

  // ---- write x_T ----
  #pragma unroll
  for (int q = 0; q < 4; ++q) {
    int row = ig * BB + kb * 4 + q;
    xT[(size_t)row * NDIM + jc] = xs[q];
  }
}

// ---------------- final readout: out = x_T @ h2o^T + b ----------------
__global__ void horn_out(const float* __restrict__ xT, const float* __restrict__ h2o_w,
                         const float* __restrict__ h2o_b, float* __restrict__ out) {
  int b = blockIdx.x;
  int lane = threadIdx.x;                  // 64 threads
  float p[ODIM];
  #pragma unroll
  for (int o = 0; o < ODIM; ++o) p[o] = 0.f;
  for (int it = 0; it < NDIM / 64; ++it) {
    int n = it * 64 + lane;
    float xv = xT[(size_t)b * NDIM + n];
    #pragma unroll
    for (int o = 0; o < ODIM; ++o) p[o] += xv * h2o_w[o * NDIM + n];
  }
  #pragma unroll
  for (int o = 0; o < ODIM; ++o) {
    float v = p[o];
    #pragma unroll
    for (int off = 32; off >= 1; off >>= 1) v += __shfl_down(v, off, 64);
    if (lane == 0) out[b * ODIM + o] = v + h2o_b[o];
  }
}

__global__ void horn_fail(float* out) {    // loud sentinel if ws too small
  int i = blockIdx.x * 256 + threadIdx.x;
  if (i < BATCH_N * ODIM) out[i] = 12345.0f;
}

extern "C" void kernel_launch(void* const* d_in, const int* in_sizes, int n_in,
                              void* d_out, int out_size, void* d_ws, size_t ws_size,
                              hipStream_t stream) {
  const float* batch = (const float*)d_in[0];
  const float* i2h_w = (const float*)d_in[1];
  const float* i2h_b = (const float*)d_in[2];
  const float* h2h_w = (const float*)d_in[3];
  const float* h2h_b = (const float*)d_in[4];
  const float* h2o_w = (const float*)d_in[5];
  const float* h2o_b = (const float*)d_in[6];
  float* out = (float*)d_out;
  char* ws = (char*)d_ws;

  if (ws_size < WS_NEED) {
    horn_fail<<<16, 256, 0, stream>>>(out);
    return;
  }

  hipMemsetAsync(ws + YBUF_OFF, 0, YBUF_HALF, stream);   // y_0 = 0
  hipMemsetAsync(ws + SEQ_OFF, 0, SEQ_BYTES, stream);    // counters = 0

  horn_convert<<<8192, 256, 0, stream>>>(batch, (unsigned short*)(ws + 0));

  horn_persistent<<<AGRP * BSLC, THREADS, 0, stream>>>(
      (const unsigned short*)(ws + 0), i2h_w, i2h_b, h2h_w, h2h_b,
      (unsigned short*)(ws + YBUF_OFF), (unsigned int*)(ws + SEQ_OFF),
      (float*)(ws + XT_OFF));

  horn_out<<<BATCH_N, 64, 0, stream>>>((const float*)(ws + XT_OFF), h2o_w, h2o_b, out);
}